// Round 9
// baseline (74.393 us; speedup 1.0000x reference)
//
#include <hip/hip_runtime.h>
#include <math.h>

#define N_NODES 16384
#define N_EDGES 524288
#define C_IN    128
#define C_HID   64
#define C_OUT   16
#define CAP     128   // max stored in-edges/node; P(deg>128)~1e-30 for Poisson(32)

// ---------------------------------------------------------------------------
// Fused: binned-CSR build (2 edges/thread) + h1 = x @ W1 (16 nodes/block,
// 4 outputs/thread). Grid 1024 x 256 (proven r5 structure).
__global__ __launch_bounds__(256) void k_gemm1_bin(const float* __restrict__ x,
                                                   const float* __restrict__ W1,
                                                   float* __restrict__ h1,
                                                   const int* __restrict__ src,
                                                   const int* __restrict__ dst,
                                                   int* __restrict__ cnt,
                                                   int* __restrict__ csr) {
    __shared__ float sW[C_IN][C_HID];   // 32 KB
    __shared__ float sx[16][C_IN];      // 8 KB
    int tid = threadIdx.x;
    int e = (blockIdx.x * 256 + tid) * 2;

    int2 s2 = *(const int2*)&src[e];
    int2 d2 = *(const int2*)&dst[e];
    int slot0 = atomicAdd(&cnt[d2.x], 1);
    int slot1 = atomicAdd(&cnt[d2.y], 1);
    if (slot0 < CAP) csr[d2.x * CAP + slot0] = s2.x;
    if (slot1 < CAP) csr[d2.y * CAP + slot1] = s2.y;

    const float4* W4 = (const float4*)W1;
    float4* sW4 = (float4*)sW;
    for (int i = tid; i < C_IN * C_HID / 4; i += 256) sW4[i] = W4[i];
    const float4* x4 = (const float4*)(x + (size_t)blockIdx.x * 16 * C_IN);
    float4* sx4 = (float4*)sx;
    for (int i = tid; i < 16 * C_IN / 4; i += 256) sx4[i] = x4[i];
    __syncthreads();

    int w = tid >> 6, col = tid & 63;
    float a0 = 0.f, a1 = 0.f, a2 = 0.f, a3 = 0.f;
#pragma unroll 8
    for (int k = 0; k < C_IN; ++k) {
        float wv = sW[k][col];
        a0 = fmaf(sx[w][k],      wv, a0);
        a1 = fmaf(sx[w + 4][k],  wv, a1);
        a2 = fmaf(sx[w + 8][k],  wv, a2);
        a3 = fmaf(sx[w + 12][k], wv, a3);
    }
    int node0 = blockIdx.x * 16;
    h1[(node0 + w) * C_HID + col]      = a0;
    h1[(node0 + w + 4) * C_HID + col]  = a1;
    h1[(node0 + w + 8) * C_HID + col]  = a2;
    h1[(node0 + w + 12) * C_HID + col] = a3;
}

// ---------------------------------------------------------------------------
// Layer 1: per node (one wave), r5 mapping (4096 blocks x 4 waves).
// lane = [edge-sub 2b | chan-quad 4b]; float4 gather from binned CSR,
// on-the-fly inv = rsqrt(cnt+1), self + bias, relu, z @ W2 -> h2.
// Also materializes inv[node] for l2.
__global__ __launch_bounds__(256) void k_l1(const float* __restrict__ h1,
                                            const int* __restrict__ csr,
                                            const int* __restrict__ cnt,
                                            const float* __restrict__ b1,
                                            const float* __restrict__ W2,
                                            float* __restrict__ h2,
                                            float* __restrict__ inv) {
    __shared__ float sW[C_OUT][C_HID + 1];
    __shared__ float sz[4][C_HID];
    int tid = threadIdx.x;
    for (int i = tid; i < C_HID * C_OUT; i += 256) {
        int k = i >> 4, c = i & 15;
        sW[c][k] = W2[i];
    }
    __syncthreads();

    int w = tid >> 6, lane = tid & 63;
    int node = blockIdx.x * 4 + w;
    int degf = cnt[node];                      // full degree (for norm)
    int deg = degf < CAP ? degf : CAP;         // stored edges
    int sub = lane >> 4;                       // edge subgroup 0..3
    int cq  = lane & 15;                       // channels 4cq..4cq+3
    int cbase = node * CAP;

    float4 acc = make_float4(0.f, 0.f, 0.f, 0.f);
    for (int j = sub; j < deg; j += 4) {
        int s = csr[cbase + j];                // 16 lanes same addr: broadcast
        float iv = rsqrtf((float)cnt[s] + 1.0f);
        const float4 v = *(const float4*)&h1[s * C_HID + 4 * cq];
        acc.x = fmaf(v.x, iv, acc.x);
        acc.y = fmaf(v.y, iv, acc.y);
        acc.z = fmaf(v.z, iv, acc.z);
        acc.w = fmaf(v.w, iv, acc.w);
    }
    acc.x += __shfl_xor(acc.x, 16); acc.y += __shfl_xor(acc.y, 16);
    acc.z += __shfl_xor(acc.z, 16); acc.w += __shfl_xor(acc.w, 16);
    acc.x += __shfl_xor(acc.x, 32); acc.y += __shfl_xor(acc.y, 32);
    acc.z += __shfl_xor(acc.z, 32); acc.w += __shfl_xor(acc.w, 32);

    float ivd = rsqrtf((float)degf + 1.0f);
    float iv2 = ivd * ivd;
    if (lane == 0) inv[node] = ivd;            // for l2
    const float4 self = *(const float4*)&h1[node * C_HID + 4 * cq];
    const float4 bb   = *(const float4*)&b1[4 * cq];
    if (lane < 16) {
        sz[w][4 * cq]     = fmaxf(fmaf(acc.x, ivd, fmaf(self.x, iv2, bb.x)), 0.f);
        sz[w][4 * cq + 1] = fmaxf(fmaf(acc.y, ivd, fmaf(self.y, iv2, bb.y)), 0.f);
        sz[w][4 * cq + 2] = fmaxf(fmaf(acc.z, ivd, fmaf(self.z, iv2, bb.z)), 0.f);
        sz[w][4 * cq + 3] = fmaxf(fmaf(acc.w, ivd, fmaf(self.w, iv2, bb.w)), 0.f);
    }
    // wave-synchronous LDS exchange (same wave wrote sz[w])
    int c = lane & 15, kg = lane >> 4;
    float p = 0.f;
#pragma unroll
    for (int i = 0; i < 16; ++i) {
        int k = kg * 16 + i;
        p += sz[w][k] * sW[c][k];
    }
    p += __shfl_xor(p, 16);
    p += __shfl_xor(p, 32);
    if (kg == 0) h2[node * C_OUT + c] = p;
}

// ---------------------------------------------------------------------------
// Layer 2: per node (one wave), r5 mapping. lane = [edge-sub 4b | chan-quad
// 2b]; gather h2 rows (16 edges per float4 wave-load) weighted by inv[s],
// self + bias + softmax.
__global__ __launch_bounds__(256) void k_l2(const float* __restrict__ h2,
                                            const int* __restrict__ csr,
                                            const int* __restrict__ cnt,
                                            const float* __restrict__ inv,
                                            const float* __restrict__ b2,
                                            float* __restrict__ out) {
    int tid = threadIdx.x;
    int w = tid >> 6, lane = tid & 63;
    int node = blockIdx.x * 4 + w;
    int degf = cnt[node];
    int deg = degf < CAP ? degf : CAP;
    int g  = lane >> 2;      // edge subgroup 0..15
    int cq = lane & 3;       // channels 4cq..4cq+3
    int cbase = node * CAP;

    float4 acc = make_float4(0.f, 0.f, 0.f, 0.f);
    for (int j = g; j < deg; j += 16) {
        int s = csr[cbase + j];                 // 4 lanes same addr
        float iv = inv[s];                      // precomputed by l1
        const float4 v = *(const float4*)&h2[s * C_OUT + 4 * cq];
        acc.x = fmaf(v.x, iv, acc.x);
        acc.y = fmaf(v.y, iv, acc.y);
        acc.z = fmaf(v.z, iv, acc.z);
        acc.w = fmaf(v.w, iv, acc.w);
    }
#pragma unroll
    for (int d = 4; d < 64; d <<= 1) {
        acc.x += __shfl_xor(acc.x, d); acc.y += __shfl_xor(acc.y, d);
        acc.z += __shfl_xor(acc.z, d); acc.w += __shfl_xor(acc.w, d);
    }

    float ivd = inv[node];
    float iv2 = ivd * ivd;
    const float4 self = *(const float4*)&h2[node * C_OUT + 4 * cq];
    const float4 bb   = *(const float4*)&b2[4 * cq];
    float l0  = fmaf(acc.x, ivd, fmaf(self.x, iv2, bb.x));
    float l1v = fmaf(acc.y, ivd, fmaf(self.y, iv2, bb.y));
    float l2v = fmaf(acc.z, ivd, fmaf(self.z, iv2, bb.z));
    float l3  = fmaf(acc.w, ivd, fmaf(self.w, iv2, bb.w));

    float mx = fmaxf(fmaxf(l0, l1v), fmaxf(l2v, l3));
    mx = fmaxf(mx, __shfl_xor(mx, 1));
    mx = fmaxf(mx, __shfl_xor(mx, 2));
    float e0 = expf(l0 - mx), e1 = expf(l1v - mx);
    float e2 = expf(l2v - mx), e3 = expf(l3 - mx);
    float sum = e0 + e1 + e2 + e3;
    sum += __shfl_xor(sum, 1);
    sum += __shfl_xor(sum, 2);
    float r = 1.0f / sum;
    if (lane < 4) {
        float4 o = make_float4(e0 * r, e1 * r, e2 * r, e3 * r);
        *(float4*)&out[node * C_OUT + 4 * cq] = o;
    }
}

// ---------------------------------------------------------------------------
extern "C" void kernel_launch(void* const* d_in, const int* in_sizes, int n_in,
                              void* d_out, int out_size, void* d_ws, size_t ws_size,
                              hipStream_t stream) {
    const float* x    = (const float*)d_in[0];
    const int*   eidx = (const int*)d_in[1];
    // d_in[2] = adj, unused
    const float* W1   = (const float*)d_in[3];
    const float* b1   = (const float*)d_in[4];
    const float* W2   = (const float*)d_in[5];
    const float* b2   = (const float*)d_in[6];
    float* out = (float*)d_out;

    const int* src = eidx;
    const int* dst = eidx + N_EDGES;

    char* ws = (char*)d_ws;
    int*   cnt = (int*)  (ws);                // 64 KB
    float* inv = (float*)(ws + (128 << 10));  // 64 KB
    int*   csr = (int*)  (ws + (1 << 20));    // 8 MB  (16384 x 128 ints)
    float* h1  = (float*)(ws + (16 << 20));   // 4 MB
    float* h2  = (float*)(ws + (24 << 20));   // 1 MB

    hipMemsetAsync(cnt, 0, (size_t)N_NODES * sizeof(int), stream);

    k_gemm1_bin<<<N_NODES / 16, 256, 0, stream>>>(x, W1, h1, src, dst, cnt, csr);
    k_l1<<<N_NODES / 4, 256, 0, stream>>>(h1, csr, cnt, b1, W2, h2, inv);
    k_l2<<<N_NODES / 4, 256, 0, stream>>>(h2, csr, cnt, inv, b2, out);
}

// Round 10
// 71.241 us; speedup vs baseline: 1.0443x; 1.0443x over previous
//
#include <hip/hip_runtime.h>
#include <math.h>

#define N_NODES 16384
#define N_EDGES 524288
#define C_IN    128
#define C_HID   64
#define C_OUT   16
#define CAP     128   // max stored in-edges/node; P(deg>128)~1e-30 for Poisson(32)

typedef unsigned int uint;
typedef unsigned short ushort;

// round-to-nearest-even f32 -> bf16 (values are finite; no NaN handling)
__device__ __forceinline__ ushort f2bf(float f) {
    uint u = __float_as_uint(f);
    return (ushort)((u + 0x7FFFu + ((u >> 16) & 1u)) >> 16);
}

// ---------------------------------------------------------------------------
// Fused: binned-CSR build (2 edges/thread) + h1 = x @ W1 (16 nodes/block,
// 4 outputs/thread), h1 stored as bf16. Grid 1024 x 256 (proven r5 structure).
__global__ __launch_bounds__(256) void k_gemm1_bin(const float* __restrict__ x,
                                                   const float* __restrict__ W1,
                                                   ushort* __restrict__ h1b,
                                                   const int* __restrict__ src,
                                                   const int* __restrict__ dst,
                                                   int* __restrict__ cnt,
                                                   int* __restrict__ csr) {
    __shared__ float sW[C_IN][C_HID];   // 32 KB
    __shared__ float sx[16][C_IN];      // 8 KB
    int tid = threadIdx.x;
    int e = (blockIdx.x * 256 + tid) * 2;

    int2 s2 = *(const int2*)&src[e];
    int2 d2 = *(const int2*)&dst[e];
    int slot0 = atomicAdd(&cnt[d2.x], 1);
    int slot1 = atomicAdd(&cnt[d2.y], 1);
    if (slot0 < CAP) csr[d2.x * CAP + slot0] = s2.x;
    if (slot1 < CAP) csr[d2.y * CAP + slot1] = s2.y;

    const float4* W4 = (const float4*)W1;
    float4* sW4 = (float4*)sW;
    for (int i = tid; i < C_IN * C_HID / 4; i += 256) sW4[i] = W4[i];
    const float4* x4 = (const float4*)(x + (size_t)blockIdx.x * 16 * C_IN);
    float4* sx4 = (float4*)sx;
    for (int i = tid; i < 16 * C_IN / 4; i += 256) sx4[i] = x4[i];
    __syncthreads();

    int w = tid >> 6, col = tid & 63;
    float a0 = 0.f, a1 = 0.f, a2 = 0.f, a3 = 0.f;
#pragma unroll 8
    for (int k = 0; k < C_IN; ++k) {
        float wv = sW[k][col];
        a0 = fmaf(sx[w][k],      wv, a0);
        a1 = fmaf(sx[w + 4][k],  wv, a1);
        a2 = fmaf(sx[w + 8][k],  wv, a2);
        a3 = fmaf(sx[w + 12][k], wv, a3);
    }
    int node0 = blockIdx.x * 16;
    h1b[(node0 + w) * C_HID + col]      = f2bf(a0);
    h1b[(node0 + w + 4) * C_HID + col]  = f2bf(a1);
    h1b[(node0 + w + 8) * C_HID + col]  = f2bf(a2);
    h1b[(node0 + w + 12) * C_HID + col] = f2bf(a3);
}

// ---------------------------------------------------------------------------
// Layer 1: per node (one wave), r5 mapping (4096 blocks x 4 waves).
// lane = [edge-sub 2b | chan-quad 4b]; bf16 gather (8 B/lane, half traffic),
// on-the-fly inv = rsqrt(cnt+1), self + bias, relu, z @ W2 -> h2 (bf16).
// Materializes inv[node] for l2.
__global__ __launch_bounds__(256) void k_l1(const ushort* __restrict__ h1b,
                                            const int* __restrict__ csr,
                                            const int* __restrict__ cnt,
                                            const float* __restrict__ b1,
                                            const float* __restrict__ W2,
                                            ushort* __restrict__ h2b,
                                            float* __restrict__ inv) {
    __shared__ float sW[C_OUT][C_HID + 1];
    __shared__ float sz[4][C_HID];
    int tid = threadIdx.x;
    for (int i = tid; i < C_HID * C_OUT; i += 256) {
        int k = i >> 4, c = i & 15;
        sW[c][k] = W2[i];
    }
    __syncthreads();

    int w = tid >> 6, lane = tid & 63;
    int node = blockIdx.x * 4 + w;
    int degf = cnt[node];                      // full degree (for norm)
    int deg = degf < CAP ? degf : CAP;         // stored edges
    int sub = lane >> 4;                       // edge subgroup 0..3
    int cq  = lane & 15;                       // channels 4cq..4cq+3
    int cbase = node * CAP;

    float4 acc = make_float4(0.f, 0.f, 0.f, 0.f);
    for (int j = sub; j < deg; j += 4) {
        int s = csr[cbase + j];                // 16 lanes same addr: broadcast
        float iv = rsqrtf((float)cnt[s] + 1.0f);
        uint2 raw = *(const uint2*)&h1b[s * C_HID + 4 * cq];   // 4 bf16 ch
        acc.x = fmaf(__uint_as_float(raw.x << 16),          iv, acc.x);
        acc.y = fmaf(__uint_as_float(raw.x & 0xFFFF0000u),  iv, acc.y);
        acc.z = fmaf(__uint_as_float(raw.y << 16),          iv, acc.z);
        acc.w = fmaf(__uint_as_float(raw.y & 0xFFFF0000u),  iv, acc.w);
    }
    acc.x += __shfl_xor(acc.x, 16); acc.y += __shfl_xor(acc.y, 16);
    acc.z += __shfl_xor(acc.z, 16); acc.w += __shfl_xor(acc.w, 16);
    acc.x += __shfl_xor(acc.x, 32); acc.y += __shfl_xor(acc.y, 32);
    acc.z += __shfl_xor(acc.z, 32); acc.w += __shfl_xor(acc.w, 32);

    float ivd = rsqrtf((float)degf + 1.0f);
    float iv2 = ivd * ivd;
    if (lane == 0) inv[node] = ivd;            // for l2
    uint2 sraw = *(const uint2*)&h1b[node * C_HID + 4 * cq];
    float s0 = __uint_as_float(sraw.x << 16);
    float s1 = __uint_as_float(sraw.x & 0xFFFF0000u);
    float s2v = __uint_as_float(sraw.y << 16);
    float s3 = __uint_as_float(sraw.y & 0xFFFF0000u);
    const float4 bb = *(const float4*)&b1[4 * cq];
    if (lane < 16) {
        sz[w][4 * cq]     = fmaxf(fmaf(acc.x, ivd, fmaf(s0,  iv2, bb.x)), 0.f);
        sz[w][4 * cq + 1] = fmaxf(fmaf(acc.y, ivd, fmaf(s1,  iv2, bb.y)), 0.f);
        sz[w][4 * cq + 2] = fmaxf(fmaf(acc.z, ivd, fmaf(s2v, iv2, bb.z)), 0.f);
        sz[w][4 * cq + 3] = fmaxf(fmaf(acc.w, ivd, fmaf(s3,  iv2, bb.w)), 0.f);
    }
    // wave-synchronous LDS exchange (same wave wrote sz[w])
    int c = lane & 15, kg = lane >> 4;
    float p = 0.f;
#pragma unroll
    for (int i = 0; i < 16; ++i) {
        int k = kg * 16 + i;
        p += sz[w][k] * sW[c][k];
    }
    p += __shfl_xor(p, 16);
    p += __shfl_xor(p, 32);
    if (kg == 0) h2b[node * C_OUT + c] = f2bf(p);
}

// ---------------------------------------------------------------------------
// Layer 2: per node (one wave), r5 mapping. lane = [edge-sub 4b | chan-quad
// 2b]; bf16 gather of h2 rows weighted by inv[s], self + bias + softmax.
__global__ __launch_bounds__(256) void k_l2(const ushort* __restrict__ h2b,
                                            const int* __restrict__ csr,
                                            const int* __restrict__ cnt,
                                            const float* __restrict__ inv,
                                            const float* __restrict__ b2,
                                            float* __restrict__ out) {
    int tid = threadIdx.x;
    int w = tid >> 6, lane = tid & 63;
    int node = blockIdx.x * 4 + w;
    int degf = cnt[node];
    int deg = degf < CAP ? degf : CAP;
    int g  = lane >> 2;      // edge subgroup 0..15
    int cq = lane & 3;       // channels 4cq..4cq+3
    int cbase = node * CAP;

    float4 acc = make_float4(0.f, 0.f, 0.f, 0.f);
    for (int j = g; j < deg; j += 16) {
        int s = csr[cbase + j];                 // 4 lanes same addr
        float iv = inv[s];                      // precomputed by l1
        uint2 raw = *(const uint2*)&h2b[s * C_OUT + 4 * cq];
        acc.x = fmaf(__uint_as_float(raw.x << 16),         iv, acc.x);
        acc.y = fmaf(__uint_as_float(raw.x & 0xFFFF0000u), iv, acc.y);
        acc.z = fmaf(__uint_as_float(raw.y << 16),         iv, acc.z);
        acc.w = fmaf(__uint_as_float(raw.y & 0xFFFF0000u), iv, acc.w);
    }
#pragma unroll
    for (int d = 4; d < 64; d <<= 1) {
        acc.x += __shfl_xor(acc.x, d); acc.y += __shfl_xor(acc.y, d);
        acc.z += __shfl_xor(acc.z, d); acc.w += __shfl_xor(acc.w, d);
    }

    float ivd = inv[node];
    float iv2 = ivd * ivd;
    uint2 sraw = *(const uint2*)&h2b[node * C_OUT + 4 * cq];
    float s0 = __uint_as_float(sraw.x << 16);
    float s1 = __uint_as_float(sraw.x & 0xFFFF0000u);
    float s2v = __uint_as_float(sraw.y << 16);
    float s3 = __uint_as_float(sraw.y & 0xFFFF0000u);
    const float4 bb = *(const float4*)&b2[4 * cq];
    float l0  = fmaf(acc.x, ivd, fmaf(s0,  iv2, bb.x));
    float l1v = fmaf(acc.y, ivd, fmaf(s1,  iv2, bb.y));
    float l2v = fmaf(acc.z, ivd, fmaf(s2v, iv2, bb.z));
    float l3  = fmaf(acc.w, ivd, fmaf(s3,  iv2, bb.w));

    float mx = fmaxf(fmaxf(l0, l1v), fmaxf(l2v, l3));
    mx = fmaxf(mx, __shfl_xor(mx, 1));
    mx = fmaxf(mx, __shfl_xor(mx, 2));
    float e0 = expf(l0 - mx), e1 = expf(l1v - mx);
    float e2 = expf(l2v - mx), e3 = expf(l3 - mx);
    float sum = e0 + e1 + e2 + e3;
    sum += __shfl_xor(sum, 1);
    sum += __shfl_xor(sum, 2);
    float r = 1.0f / sum;
    if (lane < 4) {
        float4 o = make_float4(e0 * r, e1 * r, e2 * r, e3 * r);
        *(float4*)&out[node * C_OUT + 4 * cq] = o;
    }
}

// ---------------------------------------------------------------------------
extern "C" void kernel_launch(void* const* d_in, const int* in_sizes, int n_in,
                              void* d_out, int out_size, void* d_ws, size_t ws_size,
                              hipStream_t stream) {
    const float* x    = (const float*)d_in[0];
    const int*   eidx = (const int*)d_in[1];
    // d_in[2] = adj, unused
    const float* W1   = (const float*)d_in[3];
    const float* b1   = (const float*)d_in[4];
    const float* W2   = (const float*)d_in[5];
    const float* b2   = (const float*)d_in[6];
    float* out = (float*)d_out;

    const int* src = eidx;
    const int* dst = eidx + N_EDGES;

    char* ws = (char*)d_ws;
    int*    cnt = (int*)   (ws);                // 64 KB
    float*  inv = (float*) (ws + (128 << 10));  // 64 KB
    int*    csr = (int*)   (ws + (1 << 20));    // 8 MB  (16384 x 128 ints)
    ushort* h1b = (ushort*)(ws + (16 << 20));   // 2 MB  (bf16)
    ushort* h2b = (ushort*)(ws + (24 << 20));   // 512 KB (bf16)

    hipMemsetAsync(cnt, 0, (size_t)N_NODES * sizeof(int), stream);

    k_gemm1_bin<<<N_NODES / 16, 256, 0, stream>>>(x, W1, h1b, src, dst, cnt, csr);
    k_l1<<<N_NODES / 4, 256, 0, stream>>>(h1b, csr, cnt, b1, W2, h2b, inv);
    k_l2<<<N_NODES / 4, 256, 0, stream>>>(h2b, csr, cnt, inv, b2, out);
}

// Round 11
// 69.736 us; speedup vs baseline: 1.0668x; 1.0216x over previous
//
#include <hip/hip_runtime.h>
#include <math.h>

#define N_NODES 16384
#define N_EDGES 524288
#define C_IN    128
#define C_HID   64
#define C_OUT   16
#define CAP     128   // max stored in-edges/node; P(deg>128)~1e-30 for Poisson(32)

typedef unsigned int uint;
typedef unsigned short ushort;

// round-to-nearest-even f32 -> bf16 (values are finite; no NaN handling)
__device__ __forceinline__ ushort f2bf(float f) {
    uint u = __float_as_uint(f);
    return (ushort)((u + 0x7FFFu + ((u >> 16) & 1u)) >> 16);
}

// ---------------------------------------------------------------------------
// Fused: binned-CSR build (2 edges/thread) + h1 = x @ W1 (16 nodes/block,
// two 8-node halves, 2 outputs/thread each), h1 stored bf16.
// LDS = 32K (W1) + 4K (x half) = 36 KB -> 4 blocks/CU with 16 KB slack.
__global__ __launch_bounds__(256) void k_gemm1_bin(const float* __restrict__ x,
                                                   const float* __restrict__ W1,
                                                   ushort* __restrict__ h1b,
                                                   const int* __restrict__ src,
                                                   const int* __restrict__ dst,
                                                   int* __restrict__ cnt,
                                                   int* __restrict__ csr) {
    __shared__ float sW[C_IN][C_HID];   // 32 KB
    __shared__ float sx[8][C_IN];       // 4 KB
    int tid = threadIdx.x;
    int e = (blockIdx.x * 256 + tid) * 2;

    int2 s2 = *(const int2*)&src[e];
    int2 d2 = *(const int2*)&dst[e];
    int slot0 = atomicAdd(&cnt[d2.x], 1);
    int slot1 = atomicAdd(&cnt[d2.y], 1);
    if (slot0 < CAP) csr[d2.x * CAP + slot0] = s2.x;
    if (slot1 < CAP) csr[d2.y * CAP + slot1] = s2.y;

    const float4* W4 = (const float4*)W1;
    float4* sW4 = (float4*)sW;
    for (int i = tid; i < C_IN * C_HID / 4; i += 256) sW4[i] = W4[i];

    int w = tid >> 6, col = tid & 63;
    for (int half = 0; half < 2; ++half) {
        if (half) __syncthreads();      // previous half's reads done
        const float4* x4 = (const float4*)(x + ((size_t)blockIdx.x * 16 + half * 8) * C_IN);
        float4* sx4 = (float4*)sx;
        for (int i = tid; i < 8 * C_IN / 4; i += 256) sx4[i] = x4[i];
        __syncthreads();                // sx (and, first time, sW) ready

        float a0 = 0.f, a1 = 0.f;
#pragma unroll 8
        for (int k = 0; k < C_IN; ++k) {
            float wv = sW[k][col];
            a0 = fmaf(sx[w][k],     wv, a0);
            a1 = fmaf(sx[w + 4][k], wv, a1);
        }
        int node0 = blockIdx.x * 16 + half * 8;
        h1b[(node0 + w) * C_HID + col]     = f2bf(a0);
        h1b[(node0 + w + 4) * C_HID + col] = f2bf(a1);
    }
}

// ---------------------------------------------------------------------------
// Layer 1: per node (one wave), 4096 blocks x 4 waves.
// lane = [edge-sub 3b | chan-oct 3b]: 8 edges in flight, 8 bf16 channels/lane
// via one uint4 (16 B) load per edge-lane. Half the loop trips of the uint2
// version. Then inv=rsqrt, self+bias, relu, z @ W2 -> h2 (bf16); writes inv[].
__global__ __launch_bounds__(256) void k_l1(const ushort* __restrict__ h1b,
                                            const int* __restrict__ csr,
                                            const int* __restrict__ cnt,
                                            const float* __restrict__ b1,
                                            const float* __restrict__ W2,
                                            ushort* __restrict__ h2b,
                                            float* __restrict__ inv) {
    __shared__ float sW[C_OUT][C_HID + 1];
    __shared__ float sz[4][C_HID];
    int tid = threadIdx.x;
    for (int i = tid; i < C_HID * C_OUT; i += 256) {
        int k = i >> 4, c = i & 15;
        sW[c][k] = W2[i];
    }
    __syncthreads();

    int w = tid >> 6, lane = tid & 63;
    int node = blockIdx.x * 4 + w;
    int degf = cnt[node];                      // full degree (for norm)
    int deg = degf < CAP ? degf : CAP;         // stored edges
    int sub = lane >> 3;                       // edge subgroup 0..7
    int co  = lane & 7;                        // channel oct: 8co..8co+7
    int cbase = node * CAP;

    float acc[8] = {0.f, 0.f, 0.f, 0.f, 0.f, 0.f, 0.f, 0.f};
    for (int j = sub; j < deg; j += 8) {
        int s = csr[cbase + j];                // 8 lanes same addr: broadcast
        float iv = rsqrtf((float)cnt[s] + 1.0f);
        uint4 raw = *(const uint4*)&h1b[s * C_HID + 8 * co];   // 8 bf16 ch
        acc[0] = fmaf(__uint_as_float(raw.x << 16),         iv, acc[0]);
        acc[1] = fmaf(__uint_as_float(raw.x & 0xFFFF0000u), iv, acc[1]);
        acc[2] = fmaf(__uint_as_float(raw.y << 16),         iv, acc[2]);
        acc[3] = fmaf(__uint_as_float(raw.y & 0xFFFF0000u), iv, acc[3]);
        acc[4] = fmaf(__uint_as_float(raw.z << 16),         iv, acc[4]);
        acc[5] = fmaf(__uint_as_float(raw.z & 0xFFFF0000u), iv, acc[5]);
        acc[6] = fmaf(__uint_as_float(raw.w << 16),         iv, acc[6]);
        acc[7] = fmaf(__uint_as_float(raw.w & 0xFFFF0000u), iv, acc[7]);
    }
#pragma unroll
    for (int i = 0; i < 8; ++i) {
        acc[i] += __shfl_xor(acc[i], 8);
        acc[i] += __shfl_xor(acc[i], 16);
        acc[i] += __shfl_xor(acc[i], 32);
    }

    float ivd = rsqrtf((float)degf + 1.0f);
    float iv2 = ivd * ivd;
    if (lane == 0) inv[node] = ivd;            // for l2
    if (lane < 8) {                            // co == lane
        uint4 sraw = *(const uint4*)&h1b[node * C_HID + 8 * lane];
        float4 ba = *(const float4*)&b1[8 * lane];
        float4 bbq = *(const float4*)&b1[8 * lane + 4];
        float selfv[8];
        selfv[0] = __uint_as_float(sraw.x << 16);
        selfv[1] = __uint_as_float(sraw.x & 0xFFFF0000u);
        selfv[2] = __uint_as_float(sraw.y << 16);
        selfv[3] = __uint_as_float(sraw.y & 0xFFFF0000u);
        selfv[4] = __uint_as_float(sraw.z << 16);
        selfv[5] = __uint_as_float(sraw.z & 0xFFFF0000u);
        selfv[6] = __uint_as_float(sraw.w << 16);
        selfv[7] = __uint_as_float(sraw.w & 0xFFFF0000u);
        float bv[8] = {ba.x, ba.y, ba.z, ba.w, bbq.x, bbq.y, bbq.z, bbq.w};
#pragma unroll
        for (int t = 0; t < 8; ++t)
            sz[w][8 * lane + t] = fmaxf(fmaf(acc[t], ivd, fmaf(selfv[t], iv2, bv[t])), 0.f);
    }
    // wave-synchronous LDS exchange (same wave wrote sz[w])
    int c = lane & 15, kg = lane >> 4;
    float p = 0.f;
#pragma unroll
    for (int i = 0; i < 16; ++i) {
        int k = kg * 16 + i;
        p += sz[w][k] * sW[c][k];
    }
    p += __shfl_xor(p, 16);
    p += __shfl_xor(p, 32);
    if (kg == 0) h2b[node * C_OUT + c] = f2bf(p);
}

// ---------------------------------------------------------------------------
// Layer 2: per node (one wave). lane = [edge-sub 4b | chan-quad 2b];
// bf16 gather of h2 rows weighted by inv[s], self + bias + softmax.
__global__ __launch_bounds__(256) void k_l2(const ushort* __restrict__ h2b,
                                            const int* __restrict__ csr,
                                            const int* __restrict__ cnt,
                                            const float* __restrict__ inv,
                                            const float* __restrict__ b2,
                                            float* __restrict__ out) {
    int tid = threadIdx.x;
    int w = tid >> 6, lane = tid & 63;
    int node = blockIdx.x * 4 + w;
    int degf = cnt[node];
    int deg = degf < CAP ? degf : CAP;
    int g  = lane >> 2;      // edge subgroup 0..15
    int cq = lane & 3;       // channels 4cq..4cq+3
    int cbase = node * CAP;
    float ivd = inv[node];

    float4 acc = make_float4(0.f, 0.f, 0.f, 0.f);
    for (int j = g; j < deg; j += 16) {
        int s = csr[cbase + j];                 // 4 lanes same addr
        float iv = inv[s];                      // precomputed by l1
        uint2 raw = *(const uint2*)&h2b[s * C_OUT + 4 * cq];
        acc.x = fmaf(__uint_as_float(raw.x << 16),         iv, acc.x);
        acc.y = fmaf(__uint_as_float(raw.x & 0xFFFF0000u), iv, acc.y);
        acc.z = fmaf(__uint_as_float(raw.y << 16),         iv, acc.z);
        acc.w = fmaf(__uint_as_float(raw.y & 0xFFFF0000u), iv, acc.w);
    }
#pragma unroll
    for (int d = 4; d < 64; d <<= 1) {
        acc.x += __shfl_xor(acc.x, d); acc.y += __shfl_xor(acc.y, d);
        acc.z += __shfl_xor(acc.z, d); acc.w += __shfl_xor(acc.w, d);
    }

    float iv2 = ivd * ivd;
    uint2 sraw = *(const uint2*)&h2b[node * C_OUT + 4 * cq];
    float s0 = __uint_as_float(sraw.x << 16);
    float s1 = __uint_as_float(sraw.x & 0xFFFF0000u);
    float s2v = __uint_as_float(sraw.y << 16);
    float s3 = __uint_as_float(sraw.y & 0xFFFF0000u);
    const float4 bb = *(const float4*)&b2[4 * cq];
    float l0  = fmaf(acc.x, ivd, fmaf(s0,  iv2, bb.x));
    float l1v = fmaf(acc.y, ivd, fmaf(s1,  iv2, bb.y));
    float l2v = fmaf(acc.z, ivd, fmaf(s2v, iv2, bb.z));
    float l3  = fmaf(acc.w, ivd, fmaf(s3,  iv2, bb.w));

    float mx = fmaxf(fmaxf(l0, l1v), fmaxf(l2v, l3));
    mx = fmaxf(mx, __shfl_xor(mx, 1));
    mx = fmaxf(mx, __shfl_xor(mx, 2));
    float e0 = expf(l0 - mx), e1 = expf(l1v - mx);
    float e2 = expf(l2v - mx), e3 = expf(l3 - mx);
    float sum = e0 + e1 + e2 + e3;
    sum += __shfl_xor(sum, 1);
    sum += __shfl_xor(sum, 2);
    float r = 1.0f / sum;
    if (lane < 4) {
        float4 o = make_float4(e0 * r, e1 * r, e2 * r, e3 * r);
        *(float4*)&out[node * C_OUT + 4 * cq] = o;
    }
}

// ---------------------------------------------------------------------------
extern "C" void kernel_launch(void* const* d_in, const int* in_sizes, int n_in,
                              void* d_out, int out_size, void* d_ws, size_t ws_size,
                              hipStream_t stream) {
    const float* x    = (const float*)d_in[0];
    const int*   eidx = (const int*)d_in[1];
    // d_in[2] = adj, unused
    const float* W1   = (const float*)d_in[3];
    const float* b1   = (const float*)d_in[4];
    const float* W2   = (const float*)d_in[5];
    const float* b2   = (const float*)d_in[6];
    float* out = (float*)d_out;

    const int* src = eidx;
    const int* dst = eidx + N_EDGES;

    char* ws = (char*)d_ws;
    int*    cnt = (int*)   (ws);                // 64 KB
    float*  inv = (float*) (ws + (128 << 10));  // 64 KB
    int*    csr = (int*)   (ws + (1 << 20));    // 8 MB  (16384 x 128 ints)
    ushort* h1b = (ushort*)(ws + (16 << 20));   // 2 MB  (bf16)
    ushort* h2b = (ushort*)(ws + (24 << 20));   // 512 KB (bf16)

    hipMemsetAsync(cnt, 0, (size_t)N_NODES * sizeof(int), stream);

    k_gemm1_bin<<<N_NODES / 16, 256, 0, stream>>>(x, W1, h1b, src, dst, cnt, csr);
    k_l1<<<N_NODES / 4, 256, 0, stream>>>(h1b, csr, cnt, b1, W2, h2b, inv);
    k_l2<<<N_NODES / 4, 256, 0, stream>>>(h2b, csr, cnt, inv, b2, out);
}

// Round 12
// 66.758 us; speedup vs baseline: 1.1144x; 1.0446x over previous
//
#include <hip/hip_runtime.h>
#include <math.h>

#define N_NODES 16384
#define N_EDGES 524288
#define C_IN    128
#define C_HID   64
#define C_OUT   16
#define CAP     128   // max stored in-edges/node; P(deg>128)~1e-30 for Poisson(32)

typedef unsigned int uint;
typedef unsigned short ushort;

// round-to-nearest-even f32 -> bf16 (values are finite; no NaN handling)
__device__ __forceinline__ ushort f2bf(float f) {
    uint u = __float_as_uint(f);
    return (ushort)((u + 0x7FFFu + ((u >> 16) & 1u)) >> 16);
}

// ---------------------------------------------------------------------------
// Fused: binned-CSR build (2 edges/thread, ushort src ids) + h1 = x @ W1
// (16 nodes/block, two 8-node halves), h1 stored bf16. LDS 36 KB.
__global__ __launch_bounds__(256) void k_gemm1_bin(const float* __restrict__ x,
                                                   const float* __restrict__ W1,
                                                   ushort* __restrict__ h1b,
                                                   const int* __restrict__ src,
                                                   const int* __restrict__ dst,
                                                   int* __restrict__ cnt,
                                                   ushort* __restrict__ csr) {
    __shared__ float sW[C_IN][C_HID];   // 32 KB
    __shared__ float sx[8][C_IN];       // 4 KB
    int tid = threadIdx.x;
    int e = (blockIdx.x * 256 + tid) * 2;

    int2 s2 = *(const int2*)&src[e];
    int2 d2 = *(const int2*)&dst[e];
    int slot0 = atomicAdd(&cnt[d2.x], 1);
    int slot1 = atomicAdd(&cnt[d2.y], 1);
    if (slot0 < CAP) csr[d2.x * CAP + slot0] = (ushort)s2.x;
    if (slot1 < CAP) csr[d2.y * CAP + slot1] = (ushort)s2.y;

    const float4* W4 = (const float4*)W1;
    float4* sW4 = (float4*)sW;
    for (int i = tid; i < C_IN * C_HID / 4; i += 256) sW4[i] = W4[i];

    int w = tid >> 6, col = tid & 63;
    for (int half = 0; half < 2; ++half) {
        if (half) __syncthreads();      // previous half's reads done
        const float4* x4 = (const float4*)(x + ((size_t)blockIdx.x * 16 + half * 8) * C_IN);
        float4* sx4 = (float4*)sx;
        for (int i = tid; i < 8 * C_IN / 4; i += 256) sx4[i] = x4[i];
        __syncthreads();                // sx (and, first time, sW) ready

        float a0 = 0.f, a1 = 0.f;
#pragma unroll 8
        for (int k = 0; k < C_IN; ++k) {
            float wv = sW[k][col];
            a0 = fmaf(sx[w][k],     wv, a0);
            a1 = fmaf(sx[w + 4][k], wv, a1);
        }
        int node0 = blockIdx.x * 16 + half * 8;
        h1b[(node0 + w) * C_HID + col]     = f2bf(a0);
        h1b[(node0 + w + 4) * C_HID + col] = f2bf(a1);
    }
}

// ---------------------------------------------------------------------------
// Layer 1: per node (one wave), 4096 blocks x 4 waves. Barrier-free.
// lane = [edge-sub 3b | chan-oct 3b]: 8 edges in flight, 8 bf16 channels/lane
// (one uint4/edge-lane). inv=rsqrt on the fly; self+bias+relu; z @ W2 -> h2
// with W2 coefficients held in registers (L1/L2-resident, no LDS staging).
__global__ __launch_bounds__(256) void k_l1(const ushort* __restrict__ h1b,
                                            const ushort* __restrict__ csr,
                                            const int* __restrict__ cnt,
                                            const float* __restrict__ b1,
                                            const float* __restrict__ W2,
                                            ushort* __restrict__ h2b,
                                            float* __restrict__ inv) {
    __shared__ float sz[4][C_HID];      // per-wave z rows (wave-synchronous)
    int tid = threadIdx.x;
    int w = tid >> 6, lane = tid & 63;
    int node = blockIdx.x * 4 + w;
    int degf = cnt[node];                      // full degree (for norm)
    int deg = degf < CAP ? degf : CAP;         // stored edges
    int sub = lane >> 3;                       // edge subgroup 0..7
    int co  = lane & 7;                        // channel oct: 8co..8co+7
    int cbase = node * CAP;

    float acc[8] = {0.f, 0.f, 0.f, 0.f, 0.f, 0.f, 0.f, 0.f};
    for (int j = sub; j < deg; j += 8) {
        int s = csr[cbase + j];                // 8 lanes same addr: broadcast
        float iv = rsqrtf((float)cnt[s] + 1.0f);
        uint4 raw = *(const uint4*)&h1b[s * C_HID + 8 * co];   // 8 bf16 ch
        acc[0] = fmaf(__uint_as_float(raw.x << 16),         iv, acc[0]);
        acc[1] = fmaf(__uint_as_float(raw.x & 0xFFFF0000u), iv, acc[1]);
        acc[2] = fmaf(__uint_as_float(raw.y << 16),         iv, acc[2]);
        acc[3] = fmaf(__uint_as_float(raw.y & 0xFFFF0000u), iv, acc[3]);
        acc[4] = fmaf(__uint_as_float(raw.z << 16),         iv, acc[4]);
        acc[5] = fmaf(__uint_as_float(raw.z & 0xFFFF0000u), iv, acc[5]);
        acc[6] = fmaf(__uint_as_float(raw.w << 16),         iv, acc[6]);
        acc[7] = fmaf(__uint_as_float(raw.w & 0xFFFF0000u), iv, acc[7]);
    }
#pragma unroll
    for (int i = 0; i < 8; ++i) {
        acc[i] += __shfl_xor(acc[i], 8);
        acc[i] += __shfl_xor(acc[i], 16);
        acc[i] += __shfl_xor(acc[i], 32);
    }

    float ivd = rsqrtf((float)degf + 1.0f);
    float iv2 = ivd * ivd;
    if (lane == 0) inv[node] = ivd;            // for l2
    if (lane < 8) {                            // co == lane
        uint4 sraw = *(const uint4*)&h1b[node * C_HID + 8 * lane];
        float4 ba  = *(const float4*)&b1[8 * lane];
        float4 bbq = *(const float4*)&b1[8 * lane + 4];
        float selfv[8];
        selfv[0] = __uint_as_float(sraw.x << 16);
        selfv[1] = __uint_as_float(sraw.x & 0xFFFF0000u);
        selfv[2] = __uint_as_float(sraw.y << 16);
        selfv[3] = __uint_as_float(sraw.y & 0xFFFF0000u);
        selfv[4] = __uint_as_float(sraw.z << 16);
        selfv[5] = __uint_as_float(sraw.z & 0xFFFF0000u);
        selfv[6] = __uint_as_float(sraw.w << 16);
        selfv[7] = __uint_as_float(sraw.w & 0xFFFF0000u);
        float bv[8] = {ba.x, ba.y, ba.z, ba.w, bbq.x, bbq.y, bbq.z, bbq.w};
#pragma unroll
        for (int t = 0; t < 8; ++t)
            sz[w][8 * lane + t] = fmaxf(fmaf(acc[t], ivd, fmaf(selfv[t], iv2, bv[t])), 0.f);
    }
    // wave-synchronous LDS exchange (same wave wrote sz[w])
    int c = lane & 15, kg = lane >> 4;
    float p = 0.f;
#pragma unroll
    for (int i = 0; i < 16; ++i) {
        int k = kg * 16 + i;
        p = fmaf(sz[w][k], W2[k * C_OUT + c], p);   // W2 via L1/L2, no staging
    }
    p += __shfl_xor(p, 16);
    p += __shfl_xor(p, 32);
    if (kg == 0) h2b[node * C_OUT + c] = f2bf(p);
}

// ---------------------------------------------------------------------------
// Layer 2: per node (one wave). lane = [edge-sub 4b | chan-quad 2b];
// bf16 gather of h2 rows weighted by inv[s], self + bias + softmax.
__global__ __launch_bounds__(256) void k_l2(const ushort* __restrict__ h2b,
                                            const ushort* __restrict__ csr,
                                            const int* __restrict__ cnt,
                                            const float* __restrict__ inv,
                                            const float* __restrict__ b2,
                                            float* __restrict__ out) {
    int tid = threadIdx.x;
    int w = tid >> 6, lane = tid & 63;
    int node = blockIdx.x * 4 + w;
    int degf = cnt[node];
    int deg = degf < CAP ? degf : CAP;
    int g  = lane >> 2;      // edge subgroup 0..15
    int cq = lane & 3;       // channels 4cq..4cq+3
    int cbase = node * CAP;
    float ivd = inv[node];

    float4 acc = make_float4(0.f, 0.f, 0.f, 0.f);
    for (int j = g; j < deg; j += 16) {
        int s = csr[cbase + j];                 // 4 lanes same addr
        float iv = inv[s];                      // precomputed by l1
        uint2 raw = *(const uint2*)&h2b[s * C_OUT + 4 * cq];
        acc.x = fmaf(__uint_as_float(raw.x << 16),         iv, acc.x);
        acc.y = fmaf(__uint_as_float(raw.x & 0xFFFF0000u), iv, acc.y);
        acc.z = fmaf(__uint_as_float(raw.y << 16),         iv, acc.z);
        acc.w = fmaf(__uint_as_float(raw.y & 0xFFFF0000u), iv, acc.w);
    }
#pragma unroll
    for (int d = 4; d < 64; d <<= 1) {
        acc.x += __shfl_xor(acc.x, d); acc.y += __shfl_xor(acc.y, d);
        acc.z += __shfl_xor(acc.z, d); acc.w += __shfl_xor(acc.w, d);
    }

    float iv2 = ivd * ivd;
    uint2 sraw = *(const uint2*)&h2b[node * C_OUT + 4 * cq];
    float s0  = __uint_as_float(sraw.x << 16);
    float s1  = __uint_as_float(sraw.x & 0xFFFF0000u);
    float s2v = __uint_as_float(sraw.y << 16);
    float s3  = __uint_as_float(sraw.y & 0xFFFF0000u);
    const float4 bb = *(const float4*)&b2[4 * cq];
    float l0  = fmaf(acc.x, ivd, fmaf(s0,  iv2, bb.x));
    float l1v = fmaf(acc.y, ivd, fmaf(s1,  iv2, bb.y));
    float l2v = fmaf(acc.z, ivd, fmaf(s2v, iv2, bb.z));
    float l3  = fmaf(acc.w, ivd, fmaf(s3,  iv2, bb.w));

    float mx = fmaxf(fmaxf(l0, l1v), fmaxf(l2v, l3));
    mx = fmaxf(mx, __shfl_xor(mx, 1));
    mx = fmaxf(mx, __shfl_xor(mx, 2));
    float e0 = expf(l0 - mx), e1 = expf(l1v - mx);
    float e2 = expf(l2v - mx), e3 = expf(l3 - mx);
    float sum = e0 + e1 + e2 + e3;
    sum += __shfl_xor(sum, 1);
    sum += __shfl_xor(sum, 2);
    float r = 1.0f / sum;
    if (lane < 4) {
        float4 o = make_float4(e0 * r, e1 * r, e2 * r, e3 * r);
        *(float4*)&out[node * C_OUT + 4 * cq] = o;
    }
}

// ---------------------------------------------------------------------------
extern "C" void kernel_launch(void* const* d_in, const int* in_sizes, int n_in,
                              void* d_out, int out_size, void* d_ws, size_t ws_size,
                              hipStream_t stream) {
    const float* x    = (const float*)d_in[0];
    const int*   eidx = (const int*)d_in[1];
    // d_in[2] = adj, unused
    const float* W1   = (const float*)d_in[3];
    const float* b1   = (const float*)d_in[4];
    const float* W2   = (const float*)d_in[5];
    const float* b2   = (const float*)d_in[6];
    float* out = (float*)d_out;

    const int* src = eidx;
    const int* dst = eidx + N_EDGES;

    char* ws = (char*)d_ws;
    int*    cnt = (int*)   (ws);                // 64 KB
    float*  inv = (float*) (ws + (128 << 10));  // 64 KB
    ushort* csr = (ushort*)(ws + (1 << 20));    // 4 MB  (16384 x 128 ushort)
    ushort* h1b = (ushort*)(ws + (16 << 20));   // 2 MB  (bf16)
    ushort* h2b = (ushort*)(ws + (24 << 20));   // 512 KB (bf16)

    hipMemsetAsync(cnt, 0, (size_t)N_NODES * sizeof(int), stream);

    k_gemm1_bin<<<N_NODES / 16, 256, 0, stream>>>(x, W1, h1b, src, dst, cnt, csr);
    k_l1<<<N_NODES / 4, 256, 0, stream>>>(h1b, csr, cnt, b1, W2, h2b, inv);
    k_l2<<<N_NODES / 4, 256, 0, stream>>>(h2b, csr, cnt, inv, b2, out);
}